// Round 8
// baseline (208.601 us; speedup 1.0000x reference)
//
#include <hip/hip_runtime.h>

// Problem constants
#define Bx    2
#define Sx    2048
#define Dx    1024
#define Hx    16
#define NCx   (Sx/64)     // 32 chunks per sequence
#define BHx   (Bx*Hx)     // 32
#define Mx    (Bx*Sx)     // 4096

typedef float    f4 __attribute__((ext_vector_type(4)));
typedef _Float16 h8 __attribute__((ext_vector_type(8)));
typedef _Float16 h4 __attribute__((ext_vector_type(4)));

// async global->LDS, 16B per lane. LDS dest = wave-uniform base + lane*16.
__device__ __forceinline__ void gl2lds16(const _Float16* g, _Float16* l) {
  __builtin_amdgcn_global_load_lds(
      (const __attribute__((address_space(1))) void*)g,
      (__attribute__((address_space(3))) void*)l, 16, 0, 0);
}

// ---------------------------------------------------------------------------
// convert_in: xh = (fp16)(x * mask[row]) for q,k,v in one dispatch (y selects).
// ---------------------------------------------------------------------------
__global__ __launch_bounds__(256) void convert_in(
    const float* __restrict__ q, const float* __restrict__ k,
    const float* __restrict__ v, const float* __restrict__ qm,
    const float* __restrict__ km, const float* __restrict__ vm,
    _Float16* __restrict__ qh, _Float16* __restrict__ kh,
    _Float16* __restrict__ vh)
{
  const int z = blockIdx.y;
  const float* x = (z == 0) ? q : (z == 1) ? k : v;
  const float* m = (z == 0) ? qm : (z == 1) ? km : vm;
  _Float16*    o = (z == 0) ? qh : (z == 1) ? kh : vh;
  const int i4 = blockIdx.x * 256 + threadIdx.x;   // 0..1048575
  const f4 vv = *(const f4*)(x + (size_t)i4 * 4);
  const float mf = m[i4 >> 8];
  h4 r;
  r[0] = (_Float16)(vv[0] * mf);
  r[1] = (_Float16)(vv[1] * mf);
  r[2] = (_Float16)(vv[2] * mf);
  r[3] = (_Float16)(vv[3] * mf);
  *(h4*)(o + (size_t)i4 * 4) = r;
}

// ---------------------------------------------------------------------------
// convert_w: Wt[n][k] = (fp16) W[k][n]  for 4 weights (blockIdx.z selects).
// ---------------------------------------------------------------------------
__global__ __launch_bounds__(256) void convert_w(
    const float* __restrict__ W0, const float* __restrict__ W1,
    const float* __restrict__ W2, const float* __restrict__ W3,
    _Float16* __restrict__ T0, _Float16* __restrict__ T1,
    _Float16* __restrict__ T2, _Float16* __restrict__ T3)
{
  const float* W = (blockIdx.z == 0) ? W0 : (blockIdx.z == 1) ? W1 :
                   (blockIdx.z == 2) ? W2 : W3;
  _Float16* T = (blockIdx.z == 0) ? T0 : (blockIdx.z == 1) ? T1 :
                (blockIdx.z == 2) ? T2 : T3;
  __shared__ float Ws[64 * 68];
  const int tx = threadIdx.x & 15, ty = threadIdx.x >> 4;
  const int k0 = blockIdx.y * 64, n0 = blockIdx.x * 64;
#pragma unroll
  for (int i = 0; i < 4; i++) {
    const int r = ty + 16 * i;
    *(f4*)&Ws[r * 68 + tx * 4] = *(const f4*)&W[(size_t)(k0 + r) * Dx + n0 + tx * 4];
  }
  __syncthreads();
#pragma unroll
  for (int i = 0; i < 4; i++) {
    const int n = ty + 16 * i;
    h4 o;
#pragma unroll
    for (int j = 0; j < 4; j++) o[j] = (_Float16)Ws[(tx * 4 + j) * 68 + n];
    *(h4*)&T[(size_t)(n0 + n) * Dx + k0 + tx * 4] = o;
  }
}

// ---------------------------------------------------------------------------
// gemm_f16: out[M,N] = act(A @ Bt^T + bias); m97-style global_load_lds
// staging, XOR swizzle (0 conflicts measured in R7), BK=64, 512 thr = 8 waves.
// R8: BM templated; tiles sized for >=2 blocks/CU (occupancy was 26% at 1/CU).
// ---------------------------------------------------------------------------
struct GArgs {
  const _Float16* A; const _Float16* Bt; const float* bias;
  void* out; int leaky, half_out;
};

template<int BM, int BN, int WR, int WC>
__global__ __launch_bounds__(512, 4) void gemm_f16(GArgs g0, GArgs g1, GArgs g2)
{
  const GArgs g = (blockIdx.z == 0) ? g0 : (blockIdx.z == 1) ? g1 : g2;
  constexpr int FM = BM / WR / 16;
  constexpr int FN = BN / WC / 16;
  __shared__ _Float16 As[BM * 64];
  __shared__ _Float16 Bs[BN * 64];
  const int tid = threadIdx.x;
  const int m0 = blockIdx.y * BM, n0 = blockIdx.x * BN;
  const int lane = tid & 63, wave = tid >> 6;
  const int lm = lane & 15, qd = lane >> 4;
  const int wr = wave % WR, wc = wave / WR;
  const int wm0 = wr * (BM / WR), wn0 = wc * (BN / WC);
  const int srow = lane >> 3;
  const int sseg = (lane & 7) ^ srow;
  const _Float16* gA = g.A  + (size_t)(m0 + srow) * Dx + sseg * 8;
  const _Float16* gB = g.Bt + (size_t)(n0 + srow) * Dx + sseg * 8;

  f4 acc[FM][FN];
#pragma unroll
  for (int i = 0; i < FM; i++)
#pragma unroll
    for (int j = 0; j < FN; j++) { f4 z = {0.f, 0.f, 0.f, 0.f}; acc[i][j] = z; }

  for (int kt = 0; kt < Dx; kt += 64) {
    __syncthreads();
#pragma unroll
    for (int u = 0; u < BM / 64; u++) {
      const int t = wave * (BM / 64) + u;
      gl2lds16(gA + (size_t)(t * 8) * Dx + kt, &As[t * 512]);
    }
#pragma unroll
    for (int u = 0; u < BN / 64; u++) {
      const int t = wave * (BN / 64) + u;
      gl2lds16(gB + (size_t)(t * 8) * Dx + kt, &Bs[t * 512]);
    }
    __syncthreads();
#pragma unroll
    for (int kk = 0; kk < 2; kk++) {
      const int sp = ((kk * 4 + qd) ^ (lm & 7)) * 8;
      h8 af[FM];
#pragma unroll
      for (int i = 0; i < FM; i++)
        af[i] = *(const h8*)&As[(wm0 + i * 16 + lm) * 64 + sp];
#pragma unroll
      for (int j = 0; j < FN; j++) {
        const h8 bf = *(const h8*)&Bs[(wn0 + j * 16 + lm) * 64 + sp];
#pragma unroll
        for (int i = 0; i < FM; i++)
          acc[i][j] = __builtin_amdgcn_mfma_f32_16x16x32_f16(af[i], bf, acc[i][j], 0, 0, 0);
      }
    }
  }

#pragma unroll
  for (int j = 0; j < FN; j++) {
    const int n = n0 + wn0 + j * 16 + lm;
    const float bz = g.bias[n];
#pragma unroll
    for (int i = 0; i < FM; i++) {
      const int mb = m0 + wm0 + i * 16 + qd * 4;
#pragma unroll
      for (int r = 0; r < 4; r++) {
        float v = acc[i][j][r] + bz;
        if (g.leaky) v = (v >= 0.f) ? v : 0.1f * v;
        if (g.half_out) ((_Float16*)g.out)[(size_t)(mb + r) * Dx + n] = (_Float16)v;
        else            ((float*)g.out)[(size_t)(mb + r) * Dx + n] = v;
      }
    }
  }
}

// ---------------------------------------------------------------------------
// chunkkv_mfma: S_c^T = V_c^T K_c  (64x64x64 MFMA), output fp16 [e][d];
// plus k-sums cz. 256 threads = 4 waves, wave = 16-row e-stripe.
// ---------------------------------------------------------------------------
__global__ __launch_bounds__(256) void chunkkv_mfma(
    const _Float16* __restrict__ kp, const _Float16* __restrict__ vp,
    _Float16* __restrict__ ckvh, float* __restrict__ cz)
{
  __shared__ _Float16 Kt[64 * 64];   // [d][s] swizzled
  __shared__ _Float16 Vt[64 * 64];   // [e][s] swizzled
  const int blk = blockIdx.x;
  const int c = blk & (NCx - 1);
  const int bh = blk / NCx;
  const int b = bh / Hx, h = bh % Hx;
  const int tid = threadIdx.x;
  const size_t rowbase = ((size_t)(b * Sx + c * 64)) * Dx + h * 64;

#pragma unroll
  for (int p = 0; p < 2; p++) {
    const int f = tid + 256 * p;
    const int s = f >> 3, g8 = f & 7;
    const h8 hk = *(const h8*)&kp[rowbase + (size_t)s * Dx + g8 * 8];
    const h8 hv = *(const h8*)&vp[rowbase + (size_t)s * Dx + g8 * 8];
#pragma unroll
    for (int i = 0; i < 8; i++) {
      const int r = g8 * 8 + i;       // d for Kt, e for Vt
      const int a = r * 64 + (((s >> 3) ^ (r & 7)) * 8) + (s & 7);
      Kt[a] = hk[i];
      Vt[a] = hv[i];
    }
  }
  __syncthreads();

  const int lane = tid & 63, w = tid >> 6;
  const int lm = lane & 15, qd = lane >> 4;
  const int x7 = lm & 7;

  h8 av[2];
#pragma unroll
  for (int kk = 0; kk < 2; kk++)
    av[kk] = *(const h8*)&Vt[(w * 16 + lm) * 64 + (((kk << 2) + qd) ^ x7) * 8];

#pragma unroll
  for (int dt = 0; dt < 4; dt++) {
    f4 acc = {0.f, 0.f, 0.f, 0.f};
#pragma unroll
    for (int kk = 0; kk < 2; kk++) {
      const h8 bf = *(const h8*)&Kt[(dt * 16 + lm) * 64 + (((kk << 2) + qd) ^ x7) * 8];
      acc = __builtin_amdgcn_mfma_f32_16x16x32_f16(av[kk], bf, acc, 0, 0, 0);
    }
#pragma unroll
    for (int r = 0; r < 4; r++) {
      const int e = w * 16 + qd * 4 + r;
      ckvh[(size_t)blk * 4096 + e * 64 + dt * 16 + lm] = (_Float16)acc[r];
    }
  }

  {
    const int d = tid >> 2, fr = tid & 3;
    float dp = 0.f;
#pragma unroll
    for (int j = 0; j < 2; j++) {
      const h8 kv = *(const h8*)&Kt[d * 64 + (fr * 2 + j) * 8];
#pragma unroll
      for (int i = 0; i < 8; i++) dp += (float)kv[i];
    }
    dp += __shfl_xor(dp, 1);
    dp += __shfl_xor(dp, 2);
    if (fr == 0) cz[(size_t)blk * 64 + d] = dp;
  }
}

// ---------------------------------------------------------------------------
// prefix: element-parallel exclusive scan over 32 chunks (fp16 data, fp32
// carry). 512 blocks x 256.
// ---------------------------------------------------------------------------
__global__ __launch_bounds__(256) void prefix_kernel(
    _Float16* __restrict__ ckvh, float* __restrict__ cz)
{
  const int gid = blockIdx.x * 256 + threadIdx.x;   // 0..131071
  const int bh = gid >> 12, el = gid & 4095;
  float acc = 0.f;
  for (int c = 0; c < NCx; c++) {
    const size_t idx = ((size_t)(bh * NCx + c) << 12) + el;
    const float v = (float)ckvh[idx];
    ckvh[idx] = (_Float16)acc;
    acc += v;
  }
  if (gid < BHx * 64) {
    const int zbh = gid >> 6, d = gid & 63;
    float az = 0.f;
    for (int c = 0; c < NCx; c++) {
      const size_t zi = (size_t)(zbh * NCx + c) * 64 + d;
      const float v = cz[zi];
      cz[zi] = az;
      az += v;
    }
  }
}

// ---------------------------------------------------------------------------
// attn_mfma (unchanged from R7): P = tril(Q K^T) via MFMA; O = P@V + Q@S_excl
// via MFMA; den = q.z_excl + rowsum(P). 256 thr, LDS 32.5 KB -> 4 blocks/CU.
// ---------------------------------------------------------------------------
__global__ __launch_bounds__(256) void attn_mfma(
    const _Float16* __restrict__ qp, const _Float16* __restrict__ kp,
    const _Float16* __restrict__ vp, const _Float16* __restrict__ ckvh,
    const float* __restrict__ cz, _Float16* __restrict__ concat)
{
  __shared__ _Float16 Qs[64 * 64];   // [t][d] swizzled
  __shared__ _Float16 Ks[64 * 64];   // [s][d] swizzled; reused as Pa [t][s]
  __shared__ _Float16 Vt[64 * 64];   // [e][s] swizzled
  __shared__ _Float16 Sh[64 * 64];   // [e][d] swizzled (S_excl^T fp16)
  __shared__ float zs[64];
  __shared__ float den[64];
  const int blk = blockIdx.x;
  const int c = blk & (NCx - 1);
  const int bh = blk / NCx;
  const int b = bh / Hx, h = bh % Hx;
  const int tid = threadIdx.x;
  const size_t rowbase = ((size_t)(b * Sx + c * 64)) * Dx + h * 64;

#pragma unroll
  for (int p = 0; p < 2; p++) {
    const int f = tid + 256 * p;
    const int r = f >> 3, sg = f & 7;
    const int ph = (sg ^ (r & 7)) * 8;
    *(h8*)&Qs[r * 64 + ph] = *(const h8*)&qp[rowbase + (size_t)r * Dx + sg * 8];
    *(h8*)&Ks[r * 64 + ph] = *(const h8*)&kp[rowbase + (size_t)r * Dx + sg * 8];
    *(h8*)&Sh[r * 64 + ph] = *(const h8*)&ckvh[(size_t)blk * 4096 + r * 64 + sg * 8];
  }
#pragma unroll
  for (int p = 0; p < 2; p++) {
    const int f = tid + 256 * p;
    const int s = f >> 3, g8 = f & 7;
    const h8 hv = *(const h8*)&vp[rowbase + (size_t)s * Dx + g8 * 8];
#pragma unroll
    for (int i = 0; i < 8; i++) {
      const int e = g8 * 8 + i;
      Vt[e * 64 + (((s >> 3) ^ (e & 7)) * 8) + (s & 7)] = hv[i];
    }
  }
  if (tid < 64) zs[tid] = cz[(size_t)blk * 64 + tid];
  __syncthreads();

  const int lane = tid & 63, w = tid >> 6;
  const int lm = lane & 15, qd = lane >> 4;
  const int x7 = lm & 7;

  h8 aq[2];
#pragma unroll
  for (int kk = 0; kk < 2; kk++)
    aq[kk] = *(const h8*)&Qs[(w * 16 + lm) * 64 + (((kk << 2) + qd) ^ x7) * 8];

  f4 pc[4];
#pragma unroll
  for (int st = 0; st < 4; st++) {
    f4 z4 = {0.f, 0.f, 0.f, 0.f}; pc[st] = z4;
#pragma unroll
    for (int kk = 0; kk < 2; kk++) {
      const h8 bf = *(const h8*)&Ks[(st * 16 + lm) * 64 + (((kk << 2) + qd) ^ x7) * 8];
      pc[st] = __builtin_amdgcn_mfma_f32_16x16x32_f16(aq[kk], bf, pc[st], 0, 0, 0);
    }
  }
  float rsum[4] = {0.f, 0.f, 0.f, 0.f};
#pragma unroll
  for (int st = 0; st < 4; st++) {
    const int s = st * 16 + lm;
#pragma unroll
    for (int r = 0; r < 4; r++) {
      const int t = w * 16 + qd * 4 + r;
      float v = pc[st][r];
      v = (s <= t) ? v : 0.f;
      pc[st][r] = v;
      rsum[r] += v;
    }
  }
#pragma unroll
  for (int r = 0; r < 4; r++) {
    rsum[r] += __shfl_xor(rsum[r], 1);
    rsum[r] += __shfl_xor(rsum[r], 2);
    rsum[r] += __shfl_xor(rsum[r], 4);
    rsum[r] += __shfl_xor(rsum[r], 8);
  }
  {
    const int t = tid >> 2, fr = tid & 3;
    float dp = 0.f;
#pragma unroll
    for (int j = 0; j < 2; j++) {
      const int sg = fr * 2 + j;
      const h8 qv = *(const h8*)&Qs[t * 64 + (sg ^ (t & 7)) * 8];
#pragma unroll
      for (int i = 0; i < 8; i++) dp += (float)qv[i] * zs[sg * 8 + i];
    }
    dp += __shfl_xor(dp, 1);
    dp += __shfl_xor(dp, 2);
    if (fr == 0) den[t] = dp;
  }
  __syncthreads();

  _Float16* Pa = Ks;
#pragma unroll
  for (int st = 0; st < 4; st++) {
#pragma unroll
    for (int r = 0; r < 4; r++) {
      const int row = w * 16 + qd * 4 + r;
      Pa[row * 64 + (((st * 2 + (lm >> 3)) ^ (row & 7)) * 8) + (lm & 7)] =
          (_Float16)pc[st][r];
    }
  }
  if (lm == 0) {
#pragma unroll
    for (int r = 0; r < 4; r++) den[w * 16 + qd * 4 + r] += rsum[r];
  }
  __syncthreads();

  h8 ap[2];
#pragma unroll
  for (int kk = 0; kk < 2; kk++)
    ap[kk] = *(const h8*)&Pa[(w * 16 + lm) * 64 + (((kk << 2) + qd) ^ x7) * 8];

  f4 acc[4];
#pragma unroll
  for (int et = 0; et < 4; et++) {
    f4 z4 = {0.f, 0.f, 0.f, 0.f}; acc[et] = z4;
#pragma unroll
    for (int kk = 0; kk < 2; kk++) {
      const h8 bv = *(const h8*)&Vt[(et * 16 + lm) * 64 + (((kk << 2) + qd) ^ x7) * 8];
      acc[et] = __builtin_amdgcn_mfma_f32_16x16x32_f16(ap[kk], bv, acc[et], 0, 0, 0);
    }
#pragma unroll
    for (int kk = 0; kk < 2; kk++) {
      const h8 bs = *(const h8*)&Sh[(et * 16 + lm) * 64 + (((kk << 2) + qd) ^ x7) * 8];
      acc[et] = __builtin_amdgcn_mfma_f32_16x16x32_f16(aq[kk], bs, acc[et], 0, 0, 0);
    }
  }

#pragma unroll
  for (int r = 0; r < 4; r++) {
    const int row = w * 16 + qd * 4 + r;
    const float inv = 1.f / den[row];
    _Float16* orow = &concat[((size_t)(b * Sx + c * 64 + row)) * Dx + h * 64];
#pragma unroll
    for (int et = 0; et < 4; et++)
      orow[et * 16 + lm] = (_Float16)(acc[et][r] * inv);
  }
}

// ---------------------------------------------------------------------------
extern "C" void kernel_launch(void* const* d_in, const int* in_sizes, int n_in,
                              void* d_out, int out_size, void* d_ws, size_t ws_size,
                              hipStream_t stream)
{
  const float* q  = (const float*)d_in[0];
  const float* k  = (const float*)d_in[1];
  const float* v  = (const float*)d_in[2];
  const float* qm = (const float*)d_in[3];
  const float* km = (const float*)d_in[4];
  const float* vm = (const float*)d_in[5];
  const float* Wq = (const float*)d_in[6];
  const float* bq = (const float*)d_in[7];
  const float* Wk = (const float*)d_in[8];
  const float* bk = (const float*)d_in[9];
  const float* Wv = (const float*)d_in[10];
  const float* bv = (const float*)d_in[11];
  const float* Wo = (const float*)d_in[12];
  const float* bo = (const float*)d_in[13];
  float* out = (float*)d_out;

  // workspace layout (bytes), total 56.25 MB (same as proven R7).
  char* ws = (char*)d_ws;
  _Float16* qh  = (_Float16*)(ws);                 //  8 MB
  _Float16* kh  = (_Float16*)(ws + 8388608);       //  8 MB
  _Float16* vh  = (_Float16*)(ws + 16777216);      //  8 MB
  _Float16* Wtq = (_Float16*)(ws + 25165824);      //  2 MB each
  _Float16* Wtk = (_Float16*)(ws + 27262976);
  _Float16* Wtv = (_Float16*)(ws + 29360128);
  _Float16* Wto = (_Float16*)(ws + 31457280);
  _Float16* qp  = (_Float16*)(ws + 33554432);      //  8 MB
  _Float16* kp  = (_Float16*)(ws + 41943040);      //  8 MB
  _Float16* vp  = (_Float16*)(ws + 50331648);      //  8 MB
  float*    cz  = (float*)   (ws + 58720256);      //  256 KB
  _Float16* ckvh   = qh;                           //  8 MB over dead qh
  _Float16* concat = kh;                           //  8 MB over dead kh

  convert_in<<<dim3(4096, 3), 256, 0, stream>>>(q, k, v, qm, km, vm, qh, kh, vh);
  convert_w<<<dim3(16, 16, 4), 256, 0, stream>>>(Wq, Wk, Wv, Wo, Wtq, Wtk, Wtv, Wto);

  GArgs gq = { qh, Wtq, bq, qp, 1, 1 };
  GArgs gk = { kh, Wtk, bk, kp, 1, 1 };
  GArgs gv = { vh, Wtv, bv, vp, 0, 1 };
  // 128x128 tile -> grid (8,32,3) = 768 blocks = 3/CU target (was 384 = 1.5/CU)
  gemm_f16<128, 128, 2, 4><<<dim3(Dx / 128, Mx / 128, 3), 512, 0, stream>>>(gq, gk, gv);

  chunkkv_mfma<<<BHx * NCx, 256, 0, stream>>>(kp, vp, ckvh, cz);
  prefix_kernel<<<512, 256, 0, stream>>>(ckvh, cz);
  attn_mfma<<<BHx * NCx, 256, 0, stream>>>(qp, kp, vp, ckvh, cz, concat);

  GArgs go = { concat, Wto, bo, out, 0, 0 };
  // 64x128 tile -> grid (8,64,1) = 512 blocks = 2/CU (was 256 = 1/CU)
  gemm_f16<64, 128, 2, 4><<<dim3(Dx / 128, Mx / 64, 1), 512, 0, stream>>>(go, go, go);
}